// Round 5
// baseline (1667.128 us; speedup 1.0000x reference)
//
#include <hip/hip_runtime.h>
#include <cstdint>
#include <cstddef>

// LSTMClassifier R5: 3-role concurrent pipeline, all exchanges 2-sibling.
//   gates2 = Wih2*h1(t) [feed-forward "u", role L2in] + Whh2*h2(t-1) + bg2.
// Role L1   (blk 0..71):    h1 recurrence, 2 WGs/stream, Whh1 resident (256 regs).
// Role L2in (blk 72..143):  u = Wih2*h1(t) off the h1 ring -> u ring. No recurrence.
// Role L2rec(blk 144..215): h2 recurrence: 2-sibling h2 exchange + direct u-poll into acc.
// LL packets {2x bf16, u32 tag} via relaxed agent atomics (R3-proven). Rings:
// h1 D=16, u D=8, h2 parity-2; back-pressure via progress counters polled lazily.
// 216 WGs <= 256 CUs, 1 WG/CU (waves_per_eu(1,1)) -> all co-resident, deadlock-free
// (dependencies point strictly upstream: L2rec->L2in->L1->L1-partner).

constexpr int kN = 36, kH = 256, kG = 1024, kB = 32, kT = 128, kSpec = 6, kOut = 30;
constexpr int kHP = 264;   // LDS h stride (ushort)
constexpr int kD1 = 16;    // h1 ring depth (steps)
constexpr int kD2 = 8;     // u ring depth

typedef __bf16 bf16;
typedef __bf16 bf16x8 __attribute__((ext_vector_type(8)));
typedef float f32x4 __attribute__((ext_vector_type(4)));
typedef unsigned long long u64;
typedef unsigned int u32;

__device__ __forceinline__ float sigm(float v) { return 1.f / (1.f + __expf(-v)); }
__device__ __forceinline__ float tanh_f(float v) {
  v = fminf(15.f, fmaxf(-15.f, v));
  float e = __expf(2.f * v);
  return (e - 1.f) / (e + 1.f);
}
__device__ __forceinline__ unsigned short f2bf(float f) {
  bf16 b = (bf16)f;
  return __builtin_bit_cast(unsigned short, b);
}
__device__ __forceinline__ float bf2f(unsigned short s) {
  u32 u = ((u32)s) << 16;
  return __builtin_bit_cast(float, u);
}
__device__ __forceinline__ u64 pload(const u64* p) {
  return __hip_atomic_load(p, __ATOMIC_RELAXED, __HIP_MEMORY_SCOPE_AGENT);
}
__device__ __forceinline__ void pstore(u64* p, u64 v) {
  __hip_atomic_store(p, v, __ATOMIC_RELAXED, __HIP_MEMORY_SCOPE_AGENT);
}
__device__ __forceinline__ u32 pload32(const u32* p) {
  return __hip_atomic_load(p, __ATOMIC_RELAXED, __HIP_MEMORY_SCOPE_AGENT);
}
__device__ __forceinline__ void pstore32(u32* p, u32 v) {
  __hip_atomic_store(p, v, __ATOMIC_RELAXED, __HIP_MEMORY_SCOPE_AGENT);
}

// ---- convert + permute weights fp32 -> bf16 MFMA B-fragment order ----
__global__ __launch_bounds__(256) void k_convert(
    const float* __restrict__ wa, const float* __restrict__ wb, const float* __restrict__ wc,
    bf16* __restrict__ oa, bf16* __restrict__ ob, bf16* __restrict__ oc)
{
  const size_t total = (size_t)kN * 64 * 8 * 64;
  size_t gid = (size_t)blockIdx.x * 256 + threadIdx.x;
  if (gid >= total) return;
  const int lane = (int)(gid & 63);
  const int ks = (int)((gid >> 6) & 7);
  const int nt = (int)((gid >> 9) & 63);
  const int n = (int)(gid >> 15);
  const int g = nt * 16 + (lane & 15);
  const int k = ks * 32 + (lane >> 4) * 8;
  const size_t so = ((size_t)n * kG + g) * kH + k;

  const float4 a0 = *(const float4*)(wa + so), a1 = *(const float4*)(wa + so + 4);
  const float4 b0 = *(const float4*)(wb + so), b1 = *(const float4*)(wb + so + 4);
  const float4 c0 = *(const float4*)(wc + so), c1 = *(const float4*)(wc + so + 4);
  bf16x8 va, vb, vc;
  va[0]=(bf16)a0.x; va[1]=(bf16)a0.y; va[2]=(bf16)a0.z; va[3]=(bf16)a0.w;
  va[4]=(bf16)a1.x; va[5]=(bf16)a1.y; va[6]=(bf16)a1.z; va[7]=(bf16)a1.w;
  vb[0]=(bf16)b0.x; vb[1]=(bf16)b0.y; vb[2]=(bf16)b0.z; vb[3]=(bf16)b0.w;
  vb[4]=(bf16)b1.x; vb[5]=(bf16)b1.y; vb[6]=(bf16)b1.z; vb[7]=(bf16)b1.w;
  vc[0]=(bf16)c0.x; vc[1]=(bf16)c0.y; vc[2]=(bf16)c0.z; vc[3]=(bf16)c0.w;
  vc[4]=(bf16)c1.x; vc[5]=(bf16)c1.y; vc[6]=(bf16)c1.z; vc[7]=(bf16)c1.w;
  ((bf16x8*)oa)[gid] = va;
  ((bf16x8*)ob)[gid] = vb;
  ((bf16x8*)oc)[gid] = vc;
}

// poll 2048 packets (half of h: cols [pc0,pc0+128)), 8/thread, stage into hs
__device__ __forceinline__ void poll_half(const u64* __restrict__ base, u32 want,
                                          int tid, int pc0, unsigned short (*hs)[kHP])
{
  u64 v[8];
  u32 got = 0;
  const int li0 = tid * 8;
#pragma unroll
  for (int i = 0; i < 8; ++i)
    v[i] = pload(base + (size_t)((li0 + i) >> 7) * 256 + pc0 + ((li0 + i) & 127));
  for (;;) {
#pragma unroll
    for (int i = 0; i < 8; ++i) {
      if (!(got & (1u << i)) && (u32)(v[i] >> 32) == want) {
        got |= 1u << i;
        int li = li0 + i, m = li >> 7, c = pc0 + (li & 127);
        hs[m][c] = (unsigned short)v[i];
        hs[m + 16][c] = (unsigned short)(v[i] >> 16);
      }
    }
    if (got == 0xFFu) break;
    __builtin_amdgcn_s_sleep(1);
#pragma unroll
    for (int i = 0; i < 8; ++i)
      if (!(got & (1u << i)))
        v[i] = pload(base + (size_t)((li0 + i) >> 7) * 256 + pc0 + ((li0 + i) & 127));
  }
}

// poll full 4096 packets (all 256 cols), 16/thread in 2 phases
__device__ __forceinline__ void poll_full(const u64* __restrict__ base, u32 want,
                                          int tid, unsigned short (*hs)[kHP])
{
#pragma unroll
  for (int hf = 0; hf < 2; ++hf) {
    u64 v[8];
    u32 got = 0;
    const int li0 = hf * 2048 + tid * 8;
#pragma unroll
    for (int i = 0; i < 8; ++i) v[i] = pload(base + li0 + i);
    for (;;) {
#pragma unroll
      for (int i = 0; i < 8; ++i) {
        if (!(got & (1u << i)) && (u32)(v[i] >> 32) == want) {
          got |= 1u << i;
          int li = li0 + i, m = li >> 8, c = li & 255;
          hs[m][c] = (unsigned short)v[i];
          hs[m + 16][c] = (unsigned short)(v[i] >> 16);
        }
      }
      if (got == 0xFFu) break;
      __builtin_amdgcn_s_sleep(1);
#pragma unroll
      for (int i = 0; i < 8; ++i)
        if (!(got & (1u << i))) v[i] = pload(base + li0 + i);
    }
  }
}

// ---- the 3-role concurrent pipeline ----
__global__ __launch_bounds__(256) __attribute__((amdgpu_waves_per_eu(1, 1)))
void k_lstm(
    const float* __restrict__ x, const float* __restrict__ Wih1,
    const float* __restrict__ bih1, const float* __restrict__ bhh1,
    const float* __restrict__ bih2, const float* __restrict__ bhh2,
    const bf16* __restrict__ pk1, const bf16* __restrict__ pk2i,
    const bf16* __restrict__ pk2h, float* __restrict__ h2_final,
    u64* __restrict__ h1r, u64* __restrict__ ur, u64* __restrict__ h2p,
    u32* __restrict__ prog)
{
  const int blk = blockIdx.x;
  const int role = blk / 72, bb = blk % 72, n = bb >> 1, j = bb & 1;
  const int tid = threadIdx.x, wv = tid >> 6, lane = tid & 63;
  const int l15 = lane & 15, l4 = lane >> 4;

  __shared__ alignas(16) unsigned short hs[kB][kHP];
  __shared__ float xsh[kT][kB];
  u32* prog_in = prog;       // [36][2]: L2in's consumed-step counters (gate h1 ring)
  u32* prog_rec = prog + 72; // [36][2]: L2rec's consumed-step counters (gate u ring)

  if (role == 0) {
    // ================= L1: h1 recurrence, WG owns h-cols [j*128, j*128+128) ========
    for (int i = tid; i < kB * kT; i += 256) {
      int b = i >> 7, t = i & 127;
      xsh[t][b] = x[((size_t)b * kT + t) * kN + n];
    }
    bf16x8 W[2][4][8];
    {
      const bf16x8* base = (const bf16x8*)pk1 + (size_t)n * 32768;
#pragma unroll
      for (int jj = 0; jj < 2; ++jj)
#pragma unroll
        for (int gt = 0; gt < 4; ++gt)
#pragma unroll
          for (int ks = 0; ks < 8; ++ks)
            W[jj][gt][ks] = base[(size_t)(gt * 16 + j * 8 + wv * 2 + jj) * 512 + ks * 64 + lane];
    }
    float wih[2][4], bg[2][4];
#pragma unroll
    for (int jj = 0; jj < 2; ++jj)
#pragma unroll
      for (int gt = 0; gt < 4; ++gt) {
        int g = gt * 256 + j * 128 + wv * 32 + jj * 16 + l15;
        wih[jj][gt] = Wih1[n * kG + g];
        bg[jj][gt] = bih1[n * kG + g] + bhh1[n * kG + g];
      }
    float cst[2][2][4];
#pragma unroll
    for (int a = 0; a < 2; ++a)
#pragma unroll
      for (int b = 0; b < 2; ++b)
#pragma unroll
        for (int r = 0; r < 4; ++r) cst[a][b][r] = 0.f;

    u64* ringn = h1r + (size_t)n * kD1 * 4096;
    const int pc0 = (1 - j) * 128, myb = j * 128 + wv * 32;
    __syncthreads();

#pragma unroll 1
    for (int t = 0; t < kT; ++t) {
      if ((t & 7) == 0 && t) { // ring back-pressure: slots t..t+7 destroy steps t-16..t-9
        if (tid == 0) {
          for (;;) {
            u32 a = pload32(&prog_in[n * 2]), b = pload32(&prog_in[n * 2 + 1]);
            u32 mn = a < b ? a : b;
            if ((int)mn + 8 >= t) break;
            __builtin_amdgcn_s_sleep(2);
          }
        }
        __syncthreads();
      }
      f32x4 acc[2][2][4];
#pragma unroll
      for (int mt = 0; mt < 2; ++mt)
#pragma unroll
        for (int jj = 0; jj < 2; ++jj)
#pragma unroll
          for (int gt = 0; gt < 4; ++gt)
#pragma unroll
            for (int r = 0; r < 4; ++r)
              acc[mt][jj][gt][r] = xsh[t][mt * 16 + l4 * 4 + r] * wih[jj][gt] + bg[jj][gt];
      if (t > 0) {
        poll_half(ringn + (size_t)((t - 1) % kD1) * 4096, (u32)t, tid, pc0, hs);
        __syncthreads();
#pragma unroll
        for (int ks = 0; ks < 8; ++ks) {
          bf16x8 A0 = *(const bf16x8*)&hs[l15][ks * 32 + l4 * 8];
          bf16x8 A1 = *(const bf16x8*)&hs[16 + l15][ks * 32 + l4 * 8];
#pragma unroll
          for (int jj = 0; jj < 2; ++jj)
#pragma unroll
            for (int gt = 0; gt < 4; ++gt) {
              acc[0][jj][gt] = __builtin_amdgcn_mfma_f32_16x16x32_bf16(A0, W[jj][gt][ks], acc[0][jj][gt], 0, 0, 0);
              acc[1][jj][gt] = __builtin_amdgcn_mfma_f32_16x16x32_bf16(A1, W[jj][gt][ks], acc[1][jj][gt], 0, 0, 0);
            }
        }
      }
      float hv[2][2][4];
#pragma unroll
      for (int mt = 0; mt < 2; ++mt)
#pragma unroll
        for (int jj = 0; jj < 2; ++jj)
#pragma unroll
          for (int r = 0; r < 4; ++r) {
            float cc = sigm(acc[mt][jj][1][r]) * cst[mt][jj][r]
                     + sigm(acc[mt][jj][0][r]) * tanh_f(acc[mt][jj][2][r]);
            cst[mt][jj][r] = cc;
            hv[mt][jj][r] = sigm(acc[mt][jj][3][r]) * tanh_f(cc);
          }
      u64* pub = ringn + (size_t)(t % kD1) * 4096;
      const u64 tagw = ((u64)(u32)(t + 1)) << 32;
#pragma unroll
      for (int jj = 0; jj < 2; ++jj)
#pragma unroll
        for (int r = 0; r < 4; ++r) {
          int c = myb + jj * 16 + l15, m = l4 * 4 + r;
          pstore(&pub[(size_t)m * 256 + c],
                 tagw | ((u64)f2bf(hv[1][jj][r]) << 16) | f2bf(hv[0][jj][r]));
        }
#pragma unroll
      for (int mt = 0; mt < 2; ++mt)
#pragma unroll
        for (int jj = 0; jj < 2; ++jj)
#pragma unroll
          for (int r = 0; r < 4; ++r)
            hs[mt * 16 + l4 * 4 + r][myb + jj * 16 + l15] = f2bf(hv[mt][jj][r]);
      __syncthreads();
    }
  } else if (role == 1) {
    // ================= L2in: u(t) = Wih2 * h1(t), gate cols [j*512,(j+1)*512) ======
    bf16x8 W[8][8];
    {
      const bf16x8* base = (const bf16x8*)pk2i + (size_t)n * 32768;
#pragma unroll
      for (int tt = 0; tt < 8; ++tt)
#pragma unroll
        for (int ks = 0; ks < 8; ++ks)
          W[tt][ks] = base[(size_t)(j * 32 + wv * 8 + tt) * 512 + ks * 64 + lane];
    }
    u64* ringn = h1r + (size_t)n * kD1 * 4096;
    u64* urn = ur + (size_t)n * kD2 * 16384;

#pragma unroll 1
    for (int t = 0; t < kT; ++t) {
      if ((t & 3) == 0 && t) { // u-ring back-pressure: slots t..t+3 destroy steps t-8..t-5
        if (tid == 0) {
          for (;;) {
            u32 a = pload32(&prog_rec[n * 2]), b = pload32(&prog_rec[n * 2 + 1]);
            u32 mn = a < b ? a : b;
            if ((int)mn + 4 >= t) break;
            __builtin_amdgcn_s_sleep(2);
          }
        }
        __syncthreads();
      }
      poll_full(ringn + (size_t)(t % kD1) * 4096, (u32)(t + 1), tid, hs);
      __syncthreads();
      f32x4 acc[2][8];
#pragma unroll
      for (int mt = 0; mt < 2; ++mt)
#pragma unroll
        for (int tt = 0; tt < 8; ++tt)
#pragma unroll
          for (int r = 0; r < 4; ++r) acc[mt][tt][r] = 0.f;
#pragma unroll
      for (int ks = 0; ks < 8; ++ks) {
        bf16x8 A0 = *(const bf16x8*)&hs[l15][ks * 32 + l4 * 8];
        bf16x8 A1 = *(const bf16x8*)&hs[16 + l15][ks * 32 + l4 * 8];
#pragma unroll
        for (int tt = 0; tt < 8; ++tt) {
          acc[0][tt] = __builtin_amdgcn_mfma_f32_16x16x32_bf16(A0, W[tt][ks], acc[0][tt], 0, 0, 0);
          acc[1][tt] = __builtin_amdgcn_mfma_f32_16x16x32_bf16(A1, W[tt][ks], acc[1][tt], 0, 0, 0);
        }
      }
      u64* pub = urn + (size_t)(t % kD2) * 16384;
      const u64 tagw = ((u64)(u32)(t + 1)) << 32;
#pragma unroll
      for (int tt = 0; tt < 8; ++tt)
#pragma unroll
        for (int r = 0; r < 4; ++r) {
          int gc = (j * 32 + wv * 8 + tt) * 16 + l15, m = l4 * 4 + r;
          pstore(&pub[(size_t)m * 1024 + gc],
                 tagw | ((u64)f2bf(acc[1][tt][r]) << 16) | f2bf(acc[0][tt][r]));
        }
      if (tid == 0) pstore32(&prog_in[n * 2 + j], (u32)(t + 1)); // h1(t) consumed
      __syncthreads();
    }
  } else {
    // ================= L2rec: h2 recurrence, h2-cols [j*128,(j+1)*128) =============
    bf16x8 W[2][4][8];
    {
      const bf16x8* base = (const bf16x8*)pk2h + (size_t)n * 32768;
#pragma unroll
      for (int jj = 0; jj < 2; ++jj)
#pragma unroll
        for (int gt = 0; gt < 4; ++gt)
#pragma unroll
          for (int ks = 0; ks < 8; ++ks)
            W[jj][gt][ks] = base[(size_t)(gt * 16 + j * 8 + wv * 2 + jj) * 512 + ks * 64 + lane];
    }
    float bg[2][4];
#pragma unroll
    for (int jj = 0; jj < 2; ++jj)
#pragma unroll
      for (int gt = 0; gt < 4; ++gt) {
        int g = gt * 256 + j * 128 + wv * 32 + jj * 16 + l15;
        bg[jj][gt] = bih2[n * kG + g] + bhh2[n * kG + g];
      }
    float cst[2][2][4];
#pragma unroll
    for (int a = 0; a < 2; ++a)
#pragma unroll
      for (int b = 0; b < 2; ++b)
#pragma unroll
        for (int r = 0; r < 4; ++r) cst[a][b][r] = 0.f;

    u64* urn = ur + (size_t)n * kD2 * 16384;
    u64* h2n = h2p + (size_t)n * 2 * 4096;
    const int pc0 = (1 - j) * 128, myb = j * 128 + wv * 32;
    __syncthreads();

#pragma unroll 1
    for (int t = 0; t < kT; ++t) {
      f32x4 acc[2][2][4];
#pragma unroll
      for (int mt = 0; mt < 2; ++mt)
#pragma unroll
        for (int jj = 0; jj < 2; ++jj)
#pragma unroll
          for (int gt = 0; gt < 4; ++gt)
#pragma unroll
            for (int r = 0; r < 4; ++r) acc[mt][jj][gt][r] = bg[jj][gt];
      if (t > 0) { // partner h2(t-1) exchange first; u arrives while we MFMA
        poll_half(h2n + (size_t)((t - 1) & 1) * 4096, (u32)t, tid, pc0, hs);
        __syncthreads();
#pragma unroll
        for (int ks = 0; ks < 8; ++ks) {
          bf16x8 A0 = *(const bf16x8*)&hs[l15][ks * 32 + l4 * 8];
          bf16x8 A1 = *(const bf16x8*)&hs[16 + l15][ks * 32 + l4 * 8];
#pragma unroll
          for (int jj = 0; jj < 2; ++jj)
#pragma unroll
            for (int gt = 0; gt < 4; ++gt) {
              acc[0][jj][gt] = __builtin_amdgcn_mfma_f32_16x16x32_bf16(A0, W[jj][gt][ks], acc[0][jj][gt], 0, 0, 0);
              acc[1][jj][gt] = __builtin_amdgcn_mfma_f32_16x16x32_bf16(A1, W[jj][gt][ks], acc[1][jj][gt], 0, 0, 0);
            }
        }
      }
      { // u(t) direct-poll into acc: packet (m=l4*4+r, gc) == this lane's C positions
        const u64* us = urn + (size_t)(t % kD2) * 16384;
        const u32 want = (u32)(t + 1);
#pragma unroll
        for (int jj = 0; jj < 2; ++jj) {
          u64 v[16];
          u32 got = 0;
#pragma unroll
          for (int gt = 0; gt < 4; ++gt)
#pragma unroll
            for (int r = 0; r < 4; ++r)
              v[gt * 4 + r] = pload(us + (size_t)(l4 * 4 + r) * 1024 +
                                    (gt * 16 + j * 8 + wv * 2 + jj) * 16 + l15);
          for (;;) {
#pragma unroll
            for (int gt = 0; gt < 4; ++gt)
#pragma unroll
              for (int r = 0; r < 4; ++r) {
                int i = gt * 4 + r;
                if (!(got & (1u << i)) && (u32)(v[i] >> 32) == want) {
                  got |= 1u << i;
                  acc[0][jj][gt][r] += bf2f((unsigned short)v[i]);
                  acc[1][jj][gt][r] += bf2f((unsigned short)(v[i] >> 16));
                }
              }
            if (got == 0xFFFFu) break;
            __builtin_amdgcn_s_sleep(1);
#pragma unroll
            for (int gt = 0; gt < 4; ++gt)
#pragma unroll
              for (int r = 0; r < 4; ++r) {
                int i = gt * 4 + r;
                if (!(got & (1u << i)))
                  v[i] = pload(us + (size_t)(l4 * 4 + r) * 1024 +
                               (gt * 16 + j * 8 + wv * 2 + jj) * 16 + l15);
              }
          }
        }
      }
      float hv[2][2][4];
#pragma unroll
      for (int mt = 0; mt < 2; ++mt)
#pragma unroll
        for (int jj = 0; jj < 2; ++jj)
#pragma unroll
          for (int r = 0; r < 4; ++r) {
            float cc = sigm(acc[mt][jj][1][r]) * cst[mt][jj][r]
                     + sigm(acc[mt][jj][0][r]) * tanh_f(acc[mt][jj][2][r]);
            cst[mt][jj][r] = cc;
            hv[mt][jj][r] = sigm(acc[mt][jj][3][r]) * tanh_f(cc);
          }
      u64* pub = h2n + (size_t)(t & 1) * 4096;
      const u64 tagw = ((u64)(u32)(t + 1)) << 32;
#pragma unroll
      for (int jj = 0; jj < 2; ++jj)
#pragma unroll
        for (int r = 0; r < 4; ++r) {
          int c = myb + jj * 16 + l15, m = l4 * 4 + r;
          pstore(&pub[(size_t)m * 256 + c],
                 tagw | ((u64)f2bf(hv[1][jj][r]) << 16) | f2bf(hv[0][jj][r]));
        }
#pragma unroll
      for (int mt = 0; mt < 2; ++mt)
#pragma unroll
        for (int jj = 0; jj < 2; ++jj)
#pragma unroll
          for (int r = 0; r < 4; ++r)
            hs[mt * 16 + l4 * 4 + r][myb + jj * 16 + l15] = f2bf(hv[mt][jj][r]);
      if (t == kT - 1) {
#pragma unroll
        for (int mt = 0; mt < 2; ++mt)
#pragma unroll
          for (int jj = 0; jj < 2; ++jj)
#pragma unroll
            for (int r = 0; r < 4; ++r)
              h2_final[((size_t)n * kB + (mt * 16 + l4 * 4 + r)) * kH +
                       (myb + jj * 16 + l15)] = hv[mt][jj][r];
      }
      __syncthreads();
      if (tid == 0) pstore32(&prog_rec[n * 2 + j], (u32)(t + 1)); // u(t) consumed by all
    }
  }
}

// ---- head ----
__global__ __launch_bounds__(256) void k_head1(
    const float* __restrict__ spec, const float* __restrict__ Wspec,
    const float* __restrict__ bspec, const float* __restrict__ Wp1,
    const float* __restrict__ h2f, float* __restrict__ partial)
{
  const int kc = blockIdx.x;
  const int b = blockIdx.y;
  const int o = threadIdx.x;
  __shared__ float fs[kH];
  if (kc < kN) {
    fs[o] = h2f[((size_t)kc * kB + b) * kH + o];
  } else {
    float v = bspec[o];
#pragma unroll
    for (int s = 0; s < kSpec; ++s) v += spec[b * kSpec + s] * Wspec[s * kH + o];
    fs[o] = v;
  }
  __syncthreads();
  const float* __restrict__ wp = Wp1 + (size_t)kc * 256 * kH + o;
  float a = 0.f;
#pragma unroll 8
  for (int i = 0; i < 256; ++i) a += fs[i] * wp[(size_t)i * kH];
  partial[((size_t)kc * kB + b) * kH + o] = a;
}

__global__ __launch_bounds__(256) void k_head2(
    const float* __restrict__ bp1, const float* __restrict__ Wp2,
    const float* __restrict__ bp2, const float* __restrict__ partial,
    float* __restrict__ out)
{
  const int b = blockIdx.x;
  const int o = threadIdx.x;
  __shared__ float hid[kH];
  float a = bp1[o];
#pragma unroll
  for (int kc = 0; kc < kN + 1; ++kc) a += partial[((size_t)kc * kB + b) * kH + o];
  hid[o] = fmaxf(a, 0.f);
  __syncthreads();
  if (o < kOut) {
    float r = bp2[o];
#pragma unroll 8
    for (int h = 0; h < kH; ++h) r += hid[h] * Wp2[h * kOut + o];
    out[b * kOut + o] = r;
  }
}

extern "C" void kernel_launch(void* const* d_in, const int* in_sizes, int n_in,
                              void* d_out, int out_size, void* d_ws, size_t ws_size,
                              hipStream_t stream) {
  const float* x = (const float*)d_in[0];
  const float* spec = (const float*)d_in[1];
  const float* Wih1 = (const float*)d_in[2];
  const float* Whh1 = (const float*)d_in[3];
  const float* bih1 = (const float*)d_in[4];
  const float* bhh1 = (const float*)d_in[5];
  const float* Wih2 = (const float*)d_in[6];
  const float* Whh2 = (const float*)d_in[7];
  const float* bih2 = (const float*)d_in[8];
  const float* bhh2 = (const float*)d_in[9];
  const float* Wspec = (const float*)d_in[10];
  const float* bspec = (const float*)d_in[11];
  const float* Wp1 = (const float*)d_in[12];
  const float* bp1 = (const float*)d_in[13];
  const float* Wp2 = (const float*)d_in[14];
  const float* bp2 = (const float*)d_in[15];
  float* out = (float*)d_out;

  // ws (~120 MB): [prog 4K][pk1|pk2i|pk2h 56.6M][h1r 18.9M][ur 37.7M][h2p 2.4M][h2_final 4.7M]
  // partial overlays ur (dead after k_lstm). Ring tags (1..128) never match 0xAA poison;
  // only prog needs zeroing.
  const size_t WSZ = (size_t)kN * kG * kH;
  u32* prog = (u32*)d_ws;
  bf16* pk1 = (bf16*)((char*)d_ws + 4096);
  bf16* pk2i = pk1 + WSZ;
  bf16* pk2h = pk2i + WSZ;
  u64* h1r = (u64*)(pk2h + WSZ);
  u64* urr = h1r + (size_t)kN * kD1 * 4096;
  u64* h2p = urr + (size_t)kN * kD2 * 16384;
  float* h2_final = (float*)(h2p + (size_t)kN * 2 * 4096);
  float* partial = (float*)urr;

  hipMemsetAsync(d_ws, 0, 4096, stream); // zero progress counters only

  const size_t groups = (size_t)kN * 64 * 8 * 64;
  k_convert<<<dim3((unsigned)((groups + 255) / 256)), dim3(256), 0, stream>>>(
      Whh1, Wih2, Whh2, pk1, pk2i, pk2h);
  k_lstm<<<dim3(216), dim3(256), 0, stream>>>(
      x, Wih1, bih1, bhh1, bih2, bhh2, pk1, pk2i, pk2h, h2_final, h1r, urr, h2p, prog);
  k_head1<<<dim3(kN + 1, kB), dim3(256), 0, stream>>>(spec, Wspec, bspec, Wp1, h2_final, partial);
  k_head2<<<dim3(kB), dim3(256), 0, stream>>>(bp1, Wp2, bp2, partial, out);
}

// Round 6
// 1342.825 us; speedup vs baseline: 1.2415x; 1.2415x over previous
//
#include <hip/hip_runtime.h>
#include <cstdint>
#include <cstddef>

// LSTMClassifier R6: two concurrent recurrent chains, u computed in-place.
// Role L1 (blk 0..71, 2/stream):   h1 chain, Whh1 resident (256 VGPR), 2-sibling
//                                  half-exchange via LL packets (R5-proven).
// Role L2 (blk 72..215, 4/stream): 64 h2-cols each; Wih2+Whh2 resident (128+128).
//   Per step: poll h1(t) ring (L1 leads -> ~no wait), u-MFMA in-register,
//   poll h2(t-1) parity slot (the one real RTT), Whh2-MFMA, cell, publish.
// R5 lesson: G-wide u through global LL = 1.2 GB traffic = BW saturation. Only
// H-wide h1/h2 cross WGs here: ~0.45 GB total, far under saturation.
// LL packet = {2x bf16, u32 tag}, relaxed agent atomics, self-validating, no fences.
// 216 WGs <= 256 CUs at waves_per_eu(1,1): all co-resident, deps point upstream.

constexpr int kN = 36, kH = 256, kG = 1024, kB = 32, kT = 128, kSpec = 6, kOut = 30;
constexpr int kHP = 264;   // LDS h stride (ushort)
constexpr int kD1 = 16;    // h1 ring depth (steps)

typedef __bf16 bf16;
typedef __bf16 bf16x8 __attribute__((ext_vector_type(8)));
typedef float f32x4 __attribute__((ext_vector_type(4)));
typedef unsigned long long u64;
typedef unsigned int u32;

__device__ __forceinline__ float sigm(float v) { return 1.f / (1.f + __expf(-v)); }
__device__ __forceinline__ float tanh_f(float v) {
  v = fminf(15.f, fmaxf(-15.f, v));
  float e = __expf(2.f * v);
  return (e - 1.f) / (e + 1.f);
}
__device__ __forceinline__ unsigned short f2bf(float f) {
  bf16 b = (bf16)f;
  return __builtin_bit_cast(unsigned short, b);
}
__device__ __forceinline__ u64 pload(const u64* p) {
  return __hip_atomic_load(p, __ATOMIC_RELAXED, __HIP_MEMORY_SCOPE_AGENT);
}
__device__ __forceinline__ void pstore(u64* p, u64 v) {
  __hip_atomic_store(p, v, __ATOMIC_RELAXED, __HIP_MEMORY_SCOPE_AGENT);
}
__device__ __forceinline__ u32 pload32(const u32* p) {
  return __hip_atomic_load(p, __ATOMIC_RELAXED, __HIP_MEMORY_SCOPE_AGENT);
}
__device__ __forceinline__ void pstore32(u32* p, u32 v) {
  __hip_atomic_store(p, v, __ATOMIC_RELAXED, __HIP_MEMORY_SCOPE_AGENT);
}

// ---- convert + permute weights fp32 -> bf16 MFMA B-fragment order ----
// packed[n][nt][ks][lane]: gate col g = nt*16 + (lane&15), k = ks*32 + (lane>>4)*8 + r.
__global__ __launch_bounds__(256) void k_convert(
    const float* __restrict__ wa, const float* __restrict__ wb, const float* __restrict__ wc,
    bf16* __restrict__ oa, bf16* __restrict__ ob, bf16* __restrict__ oc)
{
  const size_t total = (size_t)kN * 64 * 8 * 64;
  size_t gid = (size_t)blockIdx.x * 256 + threadIdx.x;
  if (gid >= total) return;
  const int lane = (int)(gid & 63);
  const int ks = (int)((gid >> 6) & 7);
  const int nt = (int)((gid >> 9) & 63);
  const int n = (int)(gid >> 15);
  const int g = nt * 16 + (lane & 15);
  const int k = ks * 32 + (lane >> 4) * 8;
  const size_t so = ((size_t)n * kG + g) * kH + k;

  const float4 a0 = *(const float4*)(wa + so), a1 = *(const float4*)(wa + so + 4);
  const float4 b0 = *(const float4*)(wb + so), b1 = *(const float4*)(wb + so + 4);
  const float4 c0 = *(const float4*)(wc + so), c1 = *(const float4*)(wc + so + 4);
  bf16x8 va, vb, vc;
  va[0]=(bf16)a0.x; va[1]=(bf16)a0.y; va[2]=(bf16)a0.z; va[3]=(bf16)a0.w;
  va[4]=(bf16)a1.x; va[5]=(bf16)a1.y; va[6]=(bf16)a1.z; va[7]=(bf16)a1.w;
  vb[0]=(bf16)b0.x; vb[1]=(bf16)b0.y; vb[2]=(bf16)b0.z; vb[3]=(bf16)b0.w;
  vb[4]=(bf16)b1.x; vb[5]=(bf16)b1.y; vb[6]=(bf16)b1.z; vb[7]=(bf16)b1.w;
  vc[0]=(bf16)c0.x; vc[1]=(bf16)c0.y; vc[2]=(bf16)c0.z; vc[3]=(bf16)c0.w;
  vc[4]=(bf16)c1.x; vc[5]=(bf16)c1.y; vc[6]=(bf16)c1.z; vc[7]=(bf16)c1.w;
  ((bf16x8*)oa)[gid] = va;
  ((bf16x8*)ob)[gid] = vb;
  ((bf16x8*)oc)[gid] = vc;
}

// poll 2048 packets (cols [pc0,pc0+128)), 8/thread, stage into hs
__device__ __forceinline__ void poll_half(const u64* __restrict__ base, u32 want,
                                          int tid, int pc0, unsigned short (*hs)[kHP])
{
  u64 v[8];
  u32 got = 0;
  const int li0 = tid * 8;
#pragma unroll
  for (int i = 0; i < 8; ++i)
    v[i] = pload(base + (size_t)((li0 + i) >> 7) * 256 + pc0 + ((li0 + i) & 127));
  for (;;) {
#pragma unroll
    for (int i = 0; i < 8; ++i) {
      if (!(got & (1u << i)) && (u32)(v[i] >> 32) == want) {
        got |= 1u << i;
        int li = li0 + i, m = li >> 7, c = pc0 + (li & 127);
        hs[m][c] = (unsigned short)v[i];
        hs[m + 16][c] = (unsigned short)(v[i] >> 16);
      }
    }
    if (got == 0xFFu) break;
    __builtin_amdgcn_s_sleep(1);
#pragma unroll
    for (int i = 0; i < 8; ++i)
      if (!(got & (1u << i)))
        v[i] = pload(base + (size_t)((li0 + i) >> 7) * 256 + pc0 + ((li0 + i) & 127));
  }
}

// poll full 4096 packets (all 256 cols), 16/thread in 2 phases
__device__ __forceinline__ void poll_full(const u64* __restrict__ base, u32 want,
                                          int tid, unsigned short (*hs)[kHP])
{
#pragma unroll
  for (int hf = 0; hf < 2; ++hf) {
    u64 v[8];
    u32 got = 0;
    const int li0 = hf * 2048 + tid * 8;
#pragma unroll
    for (int i = 0; i < 8; ++i) v[i] = pload(base + li0 + i);
    for (;;) {
#pragma unroll
      for (int i = 0; i < 8; ++i) {
        if (!(got & (1u << i)) && (u32)(v[i] >> 32) == want) {
          got |= 1u << i;
          int li = li0 + i, m = li >> 8, c = li & 255;
          hs[m][c] = (unsigned short)v[i];
          hs[m + 16][c] = (unsigned short)(v[i] >> 16);
        }
      }
      if (got == 0xFFu) break;
      __builtin_amdgcn_s_sleep(1);
#pragma unroll
      for (int i = 0; i < 8; ++i)
        if (!(got & (1u << i))) v[i] = pload(base + li0 + i);
    }
  }
}

// ---- two concurrent recurrent chains ----
__global__ __launch_bounds__(256) __attribute__((amdgpu_waves_per_eu(1, 1)))
void k_lstm(
    const float* __restrict__ x, const float* __restrict__ Wih1,
    const float* __restrict__ bih1, const float* __restrict__ bhh1,
    const float* __restrict__ bih2, const float* __restrict__ bhh2,
    const bf16* __restrict__ pk1, const bf16* __restrict__ pk2i,
    const bf16* __restrict__ pk2h, float* __restrict__ h2_final,
    u64* __restrict__ h1r, u64* __restrict__ h2p, u32* __restrict__ prog)
{
  const int blk = blockIdx.x;
  const int tid = threadIdx.x, wv = tid >> 6, lane = tid & 63;
  const int l15 = lane & 15, l4 = lane >> 4;

  __shared__ alignas(16) unsigned short hs1[kB][kHP];

  if (blk < 72) {
    // ================= L1: h1 chain; WG j owns h1-cols [j*128,(j+1)*128) =========
    const int n = blk >> 1, j = blk & 1;
    __shared__ float xsh[kT][kB];
    for (int i = tid; i < kB * kT; i += 256) {
      int b = i >> 7, t = i & 127;
      xsh[t][b] = x[((size_t)b * kT + t) * kN + n];
    }
    bf16x8 W[2][4][8]; // 256 VGPRs
    {
      const bf16x8* base = (const bf16x8*)pk1 + (size_t)n * 32768;
#pragma unroll
      for (int jj = 0; jj < 2; ++jj)
#pragma unroll
        for (int gt = 0; gt < 4; ++gt)
#pragma unroll
          for (int ks = 0; ks < 8; ++ks)
            W[jj][gt][ks] = base[(size_t)(gt * 16 + j * 8 + wv * 2 + jj) * 512 + ks * 64 + lane];
    }
    float wih[2][4], bg[2][4];
#pragma unroll
    for (int jj = 0; jj < 2; ++jj)
#pragma unroll
      for (int gt = 0; gt < 4; ++gt) {
        int g = gt * 256 + j * 128 + wv * 32 + jj * 16 + l15;
        wih[jj][gt] = Wih1[n * kG + g];
        bg[jj][gt] = bih1[n * kG + g] + bhh1[n * kG + g];
      }
    float cst[2][2][4];
#pragma unroll
    for (int a = 0; a < 2; ++a)
#pragma unroll
      for (int b = 0; b < 2; ++b)
#pragma unroll
        for (int r = 0; r < 4; ++r) cst[a][b][r] = 0.f;

    u64* ringn = h1r + (size_t)n * kD1 * 4096;
    u32* pg = prog + n * 4;
    const int pc0 = (1 - j) * 128, myb = j * 128 + wv * 32;
    __syncthreads();

#pragma unroll 1
    for (int t = 0; t < kT; ++t) {
      if ((t & 7) == 0 && t) { // ring back-pressure vs slowest L2 quarter
        if (tid == 0) {
          for (;;) {
            u32 m0 = pload32(&pg[0]), m1 = pload32(&pg[1]);
            u32 m2 = pload32(&pg[2]), m3 = pload32(&pg[3]);
            u32 mn = m0 < m1 ? m0 : m1;
            mn = mn < m2 ? mn : m2;
            mn = mn < m3 ? mn : m3;
            if ((int)mn + 8 >= t) break;
            __builtin_amdgcn_s_sleep(2);
          }
        }
        __syncthreads();
      }
      f32x4 acc[2][2][4];
#pragma unroll
      for (int mt = 0; mt < 2; ++mt)
#pragma unroll
        for (int jj = 0; jj < 2; ++jj)
#pragma unroll
          for (int gt = 0; gt < 4; ++gt)
#pragma unroll
            for (int r = 0; r < 4; ++r)
              acc[mt][jj][gt][r] = xsh[t][mt * 16 + l4 * 4 + r] * wih[jj][gt] + bg[jj][gt];
      if (t > 0) {
        poll_half(ringn + (size_t)((t - 1) % kD1) * 4096, (u32)t, tid, pc0, hs1);
        __syncthreads();
#pragma unroll
        for (int ks = 0; ks < 8; ++ks) {
          bf16x8 A0 = *(const bf16x8*)&hs1[l15][ks * 32 + l4 * 8];
          bf16x8 A1 = *(const bf16x8*)&hs1[16 + l15][ks * 32 + l4 * 8];
#pragma unroll
          for (int jj = 0; jj < 2; ++jj)
#pragma unroll
            for (int gt = 0; gt < 4; ++gt) {
              acc[0][jj][gt] = __builtin_amdgcn_mfma_f32_16x16x32_bf16(A0, W[jj][gt][ks], acc[0][jj][gt], 0, 0, 0);
              acc[1][jj][gt] = __builtin_amdgcn_mfma_f32_16x16x32_bf16(A1, W[jj][gt][ks], acc[1][jj][gt], 0, 0, 0);
            }
        }
      }
      float hv[2][2][4];
#pragma unroll
      for (int mt = 0; mt < 2; ++mt)
#pragma unroll
        for (int jj = 0; jj < 2; ++jj)
#pragma unroll
          for (int r = 0; r < 4; ++r) {
            float cc = sigm(acc[mt][jj][1][r]) * cst[mt][jj][r]
                     + sigm(acc[mt][jj][0][r]) * tanh_f(acc[mt][jj][2][r]);
            cst[mt][jj][r] = cc;
            hv[mt][jj][r] = sigm(acc[mt][jj][3][r]) * tanh_f(cc);
          }
      u64* pub = ringn + (size_t)(t % kD1) * 4096;
      const u64 tagw = ((u64)(u32)(t + 1)) << 32;
#pragma unroll
      for (int jj = 0; jj < 2; ++jj)
#pragma unroll
        for (int r = 0; r < 4; ++r) {
          int c = myb + jj * 16 + l15, m = l4 * 4 + r;
          pstore(&pub[(size_t)m * 256 + c],
                 tagw | ((u64)f2bf(hv[1][jj][r]) << 16) | f2bf(hv[0][jj][r]));
        }
      // local half straight into LDS for next step
#pragma unroll
      for (int mt = 0; mt < 2; ++mt)
#pragma unroll
        for (int jj = 0; jj < 2; ++jj)
#pragma unroll
          for (int r = 0; r < 4; ++r)
            hs1[mt * 16 + l4 * 4 + r][myb + jj * 16 + l15] = f2bf(hv[mt][jj][r]);
      __syncthreads();
    }
  } else {
    // ====== L2: h2 chain; WG q owns h2-cols [q*64,(q+1)*64); u in-register =======
    const int bb = blk - 72, n = bb >> 2, q = bb & 3;
    __shared__ alignas(16) unsigned short hs2[kB][kHP];

    bf16x8 Wi[4][8], Wh[4][8]; // 128 + 128 VGPRs
    {
      const bf16x8* bi = (const bf16x8*)pk2i + (size_t)n * 32768;
      const bf16x8* bh = (const bf16x8*)pk2h + (size_t)n * 32768;
#pragma unroll
      for (int gt = 0; gt < 4; ++gt)
#pragma unroll
        for (int ks = 0; ks < 8; ++ks) {
          size_t o = (size_t)(gt * 16 + q * 4 + wv) * 512 + ks * 64 + lane;
          Wi[gt][ks] = bi[o];
          Wh[gt][ks] = bh[o];
        }
    }
    const int col = q * 64 + wv * 16 + l15;
    float bg[4];
#pragma unroll
    for (int gt = 0; gt < 4; ++gt) {
      int g = gt * 256 + col;
      bg[gt] = bih2[n * kG + g] + bhh2[n * kG + g];
    }
    float cst[2][4];
#pragma unroll
    for (int mt = 0; mt < 2; ++mt)
#pragma unroll
      for (int r = 0; r < 4; ++r) cst[mt][r] = 0.f;

    u64* ringn = h1r + (size_t)n * kD1 * 4096;
    u64* h2n = h2p + (size_t)n * 2 * 4096;
    u32* pg = prog + n * 4 + q;
    __syncthreads();

#pragma unroll 1
    for (int t = 0; t < kT; ++t) {
      // (a) h1(t) from ring (L1 leads; usually first-pass hit)
      poll_full(ringn + (size_t)(t % kD1) * 4096, (u32)(t + 1), tid, hs1);
      __syncthreads();
      if (tid == 0) pstore32(pg, (u32)(t + 1)); // h1(t) staged; slot reusable
      // (b) u = Wih2 * h1(t) + bg2, in-register
      f32x4 acc[2][4];
#pragma unroll
      for (int mt = 0; mt < 2; ++mt)
#pragma unroll
        for (int gt = 0; gt < 4; ++gt)
#pragma unroll
          for (int r = 0; r < 4; ++r) acc[mt][gt][r] = bg[gt];
#pragma unroll
      for (int ks = 0; ks < 8; ++ks) {
        bf16x8 A0 = *(const bf16x8*)&hs1[l15][ks * 32 + l4 * 8];
        bf16x8 A1 = *(const bf16x8*)&hs1[16 + l15][ks * 32 + l4 * 8];
#pragma unroll
        for (int gt = 0; gt < 4; ++gt) {
          acc[0][gt] = __builtin_amdgcn_mfma_f32_16x16x32_bf16(A0, Wi[gt][ks], acc[0][gt], 0, 0, 0);
          acc[1][gt] = __builtin_amdgcn_mfma_f32_16x16x32_bf16(A1, Wi[gt][ks], acc[1][gt], 0, 0, 0);
        }
      }
      // (c) h2(t-1) exchange (all 4 quarters incl. own) + Whh2 MFMA
      if (t > 0) {
        poll_full(h2n + (size_t)((t - 1) & 1) * 4096, (u32)t, tid, hs2);
        __syncthreads();
#pragma unroll
        for (int ks = 0; ks < 8; ++ks) {
          bf16x8 A0 = *(const bf16x8*)&hs2[l15][ks * 32 + l4 * 8];
          bf16x8 A1 = *(const bf16x8*)&hs2[16 + l15][ks * 32 + l4 * 8];
#pragma unroll
          for (int gt = 0; gt < 4; ++gt) {
            acc[0][gt] = __builtin_amdgcn_mfma_f32_16x16x32_bf16(A0, Wh[gt][ks], acc[0][gt], 0, 0, 0);
            acc[1][gt] = __builtin_amdgcn_mfma_f32_16x16x32_bf16(A1, Wh[gt][ks], acc[1][gt], 0, 0, 0);
          }
        }
      }
      // (d) cell + publish h2(t)
      float hv[2][4];
#pragma unroll
      for (int mt = 0; mt < 2; ++mt)
#pragma unroll
        for (int r = 0; r < 4; ++r) {
          float cc = sigm(acc[mt][1][r]) * cst[mt][r]
                   + sigm(acc[mt][0][r]) * tanh_f(acc[mt][2][r]);
          cst[mt][r] = cc;
          hv[mt][r] = sigm(acc[mt][3][r]) * tanh_f(cc);
        }
      u64* pub = h2n + (size_t)(t & 1) * 4096;
      const u64 tagw = ((u64)(u32)(t + 1)) << 32;
#pragma unroll
      for (int r = 0; r < 4; ++r) {
        int m = l4 * 4 + r;
        pstore(&pub[(size_t)m * 256 + col],
               tagw | ((u64)f2bf(hv[1][r]) << 16) | f2bf(hv[0][r]));
      }
      if (t == kT - 1) {
#pragma unroll
        for (int mt = 0; mt < 2; ++mt)
#pragma unroll
          for (int r = 0; r < 4; ++r)
            h2_final[((size_t)n * kB + (mt * 16 + l4 * 4 + r)) * kH + col] = hv[mt][r];
      }
      __syncthreads(); // hs1/hs2 safe for next iteration's polls
    }
  }
}

// ---- head ----
__global__ __launch_bounds__(256) void k_head1(
    const float* __restrict__ spec, const float* __restrict__ Wspec,
    const float* __restrict__ bspec, const float* __restrict__ Wp1,
    const float* __restrict__ h2f, float* __restrict__ partial)
{
  const int kc = blockIdx.x;
  const int b = blockIdx.y;
  const int o = threadIdx.x;
  __shared__ float fs[kH];
  if (kc < kN) {
    fs[o] = h2f[((size_t)kc * kB + b) * kH + o];
  } else {
    float v = bspec[o];
#pragma unroll
    for (int s = 0; s < kSpec; ++s) v += spec[b * kSpec + s] * Wspec[s * kH + o];
    fs[o] = v;
  }
  __syncthreads();
  const float* __restrict__ wp = Wp1 + (size_t)kc * 256 * kH + o;
  float a = 0.f;
#pragma unroll 8
  for (int i = 0; i < 256; ++i) a += fs[i] * wp[(size_t)i * kH];
  partial[((size_t)kc * kB + b) * kH + o] = a;
}

__global__ __launch_bounds__(256) void k_head2(
    const float* __restrict__ bp1, const float* __restrict__ Wp2,
    const float* __restrict__ bp2, const float* __restrict__ partial,
    float* __restrict__ out)
{
  const int b = blockIdx.x;
  const int o = threadIdx.x;
  __shared__ float hid[kH];
  float a = bp1[o];
#pragma unroll
  for (int kc = 0; kc < kN + 1; ++kc) a += partial[((size_t)kc * kB + b) * kH + o];
  hid[o] = fmaxf(a, 0.f);
  __syncthreads();
  if (o < kOut) {
    float r = bp2[o];
#pragma unroll 8
    for (int h = 0; h < kH; ++h) r += hid[h] * Wp2[h * kOut + o];
    out[b * kOut + o] = r;
  }
}

extern "C" void kernel_launch(void* const* d_in, const int* in_sizes, int n_in,
                              void* d_out, int out_size, void* d_ws, size_t ws_size,
                              hipStream_t stream) {
  const float* x = (const float*)d_in[0];
  const float* spec = (const float*)d_in[1];
  const float* Wih1 = (const float*)d_in[2];
  const float* Whh1 = (const float*)d_in[3];
  const float* bih1 = (const float*)d_in[4];
  const float* bhh1 = (const float*)d_in[5];
  const float* Wih2 = (const float*)d_in[6];
  const float* Whh2 = (const float*)d_in[7];
  const float* bih2 = (const float*)d_in[8];
  const float* bhh2 = (const float*)d_in[9];
  const float* Wspec = (const float*)d_in[10];
  const float* bspec = (const float*)d_in[11];
  const float* Wp1 = (const float*)d_in[12];
  const float* bp1 = (const float*)d_in[13];
  const float* Wp2 = (const float*)d_in[14];
  const float* bp2 = (const float*)d_in[15];
  float* out = (float*)d_out;

  // ws (~84 MB): [prog 4K][pk1|pk2i|pk2h 56.6M][h1r 18.9M][h2p 2.4M][h2_final 4.7M][partial 1.2M]
  // Ring tags 1..128 never match 0xAA poison; only prog needs zeroing.
  const size_t WSZ = (size_t)kN * kG * kH;
  u32* prog = (u32*)d_ws;
  bf16* pk1 = (bf16*)((char*)d_ws + 4096);
  bf16* pk2i = pk1 + WSZ;
  bf16* pk2h = pk2i + WSZ;
  u64* h1r = (u64*)(pk2h + WSZ);
  u64* h2p = h1r + (size_t)kN * kD1 * 4096;
  float* h2_final = (float*)(h2p + (size_t)kN * 2 * 4096);
  float* partial = h2_final + (size_t)kN * kB * kH;

  hipMemsetAsync(d_ws, 0, 4096, stream); // zero progress counters only

  const size_t groups = (size_t)kN * 64 * 8 * 64;
  k_convert<<<dim3((unsigned)((groups + 255) / 256)), dim3(256), 0, stream>>>(
      Whh1, Wih2, Whh2, pk1, pk2i, pk2h);
  k_lstm<<<dim3(216), dim3(256), 0, stream>>>(
      x, Wih1, bih1, bhh1, bih2, bhh2, pk1, pk2i, pk2h, h2_final, h1r, h2p, prog);
  k_head1<<<dim3(kN + 1, kB), dim3(256), 0, stream>>>(spec, Wspec, bspec, Wp1, h2_final, partial);
  k_head2<<<dim3(kB), dim3(256), 0, stream>>>(bp1, Wp2, bp2, partial, out);
}